// Round 1
// baseline (3568.932 us; speedup 1.0000x reference)
//
#include <hip/hip_runtime.h>

#define NB 1536
#define NS 1536
#define NLAYERS 5
#define TSTEPS 4

#define KC 4.4294469180704688f /* sqrt(2*9.81) */

static __device__ __forceinline__ float asqrt(float x) { return __builtin_amdgcn_sqrtf(x); }

// one spigot step; updates R, sets fl
#define STEP(tt, hh, aa)              \
  {                                   \
    float k = (tt) * ((aa)*KC);       \
    float e = fmaxf(R - (hh), 0.0f);  \
    float sq = asqrt(e);              \
    fl = k * sq;                      \
    R = fmaf(-0.5f * k, sq, R);       \
  }

// Serial scan over NS spigots for one bucket. th/hp/ap point at this bucket's
// row (s contiguous). Flows stored to fb[s*WSTRIDE]. Returns new H.
template <int WSTRIDE>
static __device__ float scan_bucket(const float* __restrict__ th,
                                    const float* __restrict__ hp,
                                    const float* __restrict__ ap, float P,
                                    float* __restrict__ fb) {
  float R = P;
  float4 t0 = *(const float4*)(th + 0), t1 = *(const float4*)(th + 4);
  float4 h0 = *(const float4*)(hp + 0), h1 = *(const float4*)(hp + 4);
  float4 a0 = *(const float4*)(ap + 0), a1 = *(const float4*)(ap + 4);
  for (int s = 0; s < NS; s += 8) {
    int sn = (s + 8 < NS) ? s + 8 : s;  // last group reloads itself (harmless)
    float4 tn0 = *(const float4*)(th + sn), tn1 = *(const float4*)(th + sn + 4);
    float4 hn0 = *(const float4*)(hp + sn), hn1 = *(const float4*)(hp + sn + 4);
    float4 an0 = *(const float4*)(ap + sn), an1 = *(const float4*)(ap + sn + 4);
    float fl;
    STEP(t0.x, h0.x, a0.x); fb[(size_t)(s + 0) * WSTRIDE] = fl;
    STEP(t0.y, h0.y, a0.y); fb[(size_t)(s + 1) * WSTRIDE] = fl;
    STEP(t0.z, h0.z, a0.z); fb[(size_t)(s + 2) * WSTRIDE] = fl;
    STEP(t0.w, h0.w, a0.w); fb[(size_t)(s + 3) * WSTRIDE] = fl;
    STEP(t1.x, h1.x, a1.x); fb[(size_t)(s + 4) * WSTRIDE] = fl;
    STEP(t1.y, h1.y, a1.y); fb[(size_t)(s + 5) * WSTRIDE] = fl;
    STEP(t1.z, h1.z, a1.z); fb[(size_t)(s + 6) * WSTRIDE] = fl;
    STEP(t1.w, h1.w, a1.w); fb[(size_t)(s + 7) * WSTRIDE] = fl;
    t0 = tn0; t1 = tn1; h0 = hn0; h1 = hn1; a0 = an0; a1 = an1;
  }
  return 2.0f * R - P;
}

static __device__ __forceinline__ float row_sum(const float* __restrict__ row) {
  const float4* r4 = (const float4*)row;
  float ax = 0.f, ay = 0.f, az = 0.f, aw = 0.f;
  float bx = 0.f, by = 0.f, bz = 0.f, bw = 0.f;
#pragma unroll 8
  for (int i = 0; i < NS / 8; ++i) {
    float4 v = r4[2 * i], w = r4[2 * i + 1];
    ax += v.x; ay += v.y; az += v.z; aw += v.w;
    bx += w.x; by += w.y; bz += w.z; bw += w.w;
  }
  return ((ax + ay) + (az + aw)) + ((bx + by) + (bz + bw));
}

__global__ void init_k(const float* __restrict__ Hinit, float* __restrict__ H,
                       float* __restrict__ out) {
  int i = blockIdx.x * 256 + threadIdx.x;
  if (i < NLAYERS * NB) H[i] = Hinit[i];
  if (i < TSTEPS) out[i] = 0.0f;
}

// Layer 0: single live bucket (bucket 0), serial over its 1536 spigots.
__global__ void layer0_k(const float* __restrict__ theta,
                         const float* __restrict__ sp_h,
                         const float* __restrict__ sp_a,
                         const float* __restrict__ precip, int t,
                         float* __restrict__ H, float* __restrict__ fb0) {
  if (threadIdx.x != 0 || blockIdx.x != 0) return;
  float ppl = precip[t] * (1.0f / NLAYERS);
  float P = H[0] + ppl;
  H[0] = scan_bucket<1>(theta, sp_h, sp_a, P, fb0);
}

// Layers 1..3: 1536 buckets, one thread each.
__global__ __launch_bounds__(256) void layerN_k(
    const float* __restrict__ theta, const float* __restrict__ sp_h,
    const float* __restrict__ sp_a, const float* __restrict__ precip, int t,
    int l, float* __restrict__ H, const float* __restrict__ fb_in,
    float* __restrict__ fb_out, int vec_in) {
  int j = blockIdx.x * 256 + threadIdx.x;
  if (j >= NB) return;
  float ppl = precip[t] * (1.0f / NLAYERS);
  float inflow = ppl * (1.0f / NB);
  if (vec_in) {
    inflow += fb_in[j];                       // layer0 -> layer1: single producer bucket
  } else {
    inflow += row_sum(fb_in + (size_t)j * NS);  // sum over upstream buckets
  }
  size_t base = ((size_t)l * NB + j) * NS;
  float P = H[l * NB + j] + inflow;
  float Hn = scan_bucket<NB>(theta + base, sp_h + base, sp_a + base, P, fb_out + j);
  H[l * NB + j] = Hn;
}

// Layer 4: one spigot per bucket; outflow = sum of flows.
__global__ __launch_bounds__(256) void layer4_k(
    const float* __restrict__ theta, const float* __restrict__ sp_h,
    const float* __restrict__ sp_a, const float* __restrict__ precip, int t,
    float* __restrict__ H, const float* __restrict__ fb3,
    float* __restrict__ out) {
  int b = blockIdx.x * 256 + threadIdx.x;
  if (b >= NB) return;
  float ppl = precip[t] * (1.0f / NLAYERS);
  float inflow = ppl * (1.0f / NB) + row_sum(fb3 + (size_t)b * NS);
  size_t idx = ((size_t)4 * NB + b) * NS;  // spigot 0
  float P = H[4 * NB + b] + inflow;
  float e = fmaxf(P - sp_h[idx], 0.0f);
  float fl = theta[idx] * (sp_a[idx] * KC) * asqrt(e);
  H[4 * NB + b] = P - fl;
  // wave64 butterfly reduce, one atomic per wave
  for (int o = 32; o; o >>= 1) fl += __shfl_xor(fl, o);
  if ((threadIdx.x & 63) == 0) atomicAdd(out + t, fl);
}

extern "C" void kernel_launch(void* const* d_in, const int* in_sizes, int n_in,
                              void* d_out, int out_size, void* d_ws,
                              size_t ws_size, hipStream_t stream) {
  const float* theta = (const float*)d_in[0];
  const float* sp_h = (const float*)d_in[1];
  const float* sp_a = (const float*)d_in[2];
  const float* Hinit = (const float*)d_in[3];
  const float* precip = (const float*)d_in[4];
  float* out = (float*)d_out;

  char* ws = (char*)d_ws;
  float* H = (float*)ws;                  // 5*1536 floats
  float* fb0 = (float*)(ws + 32768);      // 1536 floats
  float* fbA = (float*)(ws + 65536);      // NB*NS floats
  float* fbB = (float*)(ws + 65536 + (size_t)NB * NS * 4);
  // total ws use: 65536 + 2*9437184 = ~18.1 MB

  hipLaunchKernelGGL(init_k, dim3(30), dim3(256), 0, stream, Hinit, H, out);
  for (int t = 0; t < TSTEPS; ++t) {
    hipLaunchKernelGGL(layer0_k, dim3(1), dim3(64), 0, stream, theta, sp_h,
                       sp_a, precip, t, H, fb0);
    hipLaunchKernelGGL(layerN_k, dim3(6), dim3(256), 0, stream, theta, sp_h,
                       sp_a, precip, t, 1, H, fb0, fbA, 1);
    hipLaunchKernelGGL(layerN_k, dim3(6), dim3(256), 0, stream, theta, sp_h,
                       sp_a, precip, t, 2, H, fbA, fbB, 0);
    hipLaunchKernelGGL(layerN_k, dim3(6), dim3(256), 0, stream, theta, sp_h,
                       sp_a, precip, t, 3, H, fbB, fbA, 0);
    hipLaunchKernelGGL(layer4_k, dim3(6), dim3(256), 0, stream, theta, sp_h,
                       sp_a, precip, t, H, fbA, out);
  }
}

// Round 2
// 1377.278 us; speedup vs baseline: 2.5913x; 2.5913x over previous
//
#include <hip/hip_runtime.h>

#define NB 1536
#define NS 1536
#define TSTEPS 4
#define KC 4.4294469180704688f /* sqrt(2*9.81) */

// ---------------- ws layout (bytes) ----------------
// khT  : float2[3][NS][NB]   l=1..3 transposed+fused params   56,623,104
// kh0  : float2[NS]          layer0 bucket0 params                12,288
// kh4  : float2[NB]          layer4 spigot0 params                12,288
// H    : float[5*NB]                                              30,720
// fb0  : float[2][NS]        layer0 flow vector (double buf)      12,288
// fbA  : float[NB*NS]        flow matrix ping                  9,437,184
// fbB  : float[NB*NS]        flow matrix pong                  9,437,184
#define OFF_KHT 0ull
#define OFF_KH0 (OFF_KHT + 3ull * NS * NB * 8)
#define OFF_KH4 (OFF_KH0 + (unsigned long long)NS * 8)
#define OFF_H   (OFF_KH4 + (unsigned long long)NB * 8)
#define OFF_FB0 (OFF_H + 5ull * NB * 4)
#define OFF_FBA (OFF_FB0 + 2ull * NS * 4)
#define OFF_FBB (OFF_FBA + (unsigned long long)NB * NS * 4)

static __device__ __forceinline__ float asqrt(float x) { return __builtin_amdgcn_sqrtf(x); }

// one spigot step on running R: e=max(R-h,0); fl=k*sqrt(e); R-=fl/2
#define SSTEP(KX, HY, FL)                   \
  {                                         \
    float e_ = fmaxf(R - (HY), 0.0f);       \
    float q_ = asqrt(e_);                   \
    FL = (KX)*q_;                           \
    R = fmaf(-0.5f, FL, R);                 \
  }

// ---------------- prep: fuse+small tables ----------------
__global__ __launch_bounds__(256) void prep_small_k(const float* __restrict__ th,
                                                    const float* __restrict__ hh,
                                                    const float* __restrict__ aa,
                                                    float2* __restrict__ kh0,
                                                    float2* __restrict__ kh4) {
  int i = blockIdx.x * 256 + threadIdx.x;
  if (i >= NS) return;
  kh0[i] = make_float2(th[i] * aa[i] * KC, hh[i]);          // theta[0][0][i]
  size_t i4 = ((size_t)4 * NB + i) * NS;                    // theta[4][i][0]
  kh4[i] = make_float2(th[i4] * aa[i4] * KC, hh[i4]);
}

// ---------------- prep: tiled transpose for l=1..3 ----------------
// khT[(l-1)][s][b] = { theta[l][b][s]*sp_a[l][b][s]*KC , sp_h[l][b][s] }
__global__ __launch_bounds__(256) void transpose_k(const float* __restrict__ th,
                                                   const float* __restrict__ hh,
                                                   const float* __restrict__ aa,
                                                   float2* __restrict__ khT) {
  __shared__ float2 tile[64][65];
  int l = blockIdx.z + 1;
  int b0 = blockIdx.x * 64, s0 = blockIdx.y * 64;
  int lane = threadIdx.x & 63, ty = threadIdx.x >> 6;  // 4 row-groups
  size_t base = (size_t)l * NB * NS;
#pragma unroll
  for (int r = 0; r < 64; r += 4) {
    int b = b0 + r + ty;
    size_t idx = base + (size_t)b * NS + s0 + lane;
    tile[r + ty][lane] = make_float2(th[idx] * aa[idx] * KC, hh[idx]);
  }
  __syncthreads();
#pragma unroll
  for (int r = 0; r < 64; r += 4) {
    int s = s0 + r + ty;
    khT[((size_t)blockIdx.z * NS + s) * NB + b0 + lane] = tile[lane][r + ty];
  }
}

// ---------------- layer0 serial scan (single lane) ----------------
static __device__ void scan0(const float2* __restrict__ kh0, float* __restrict__ fbrow,
                             float* __restrict__ H0, float P) {
  float R = P;
  const float4* p = (const float4*)kh0;  // {k0,h0,k1,h1} per float4, 4 per 8-step group
  float4 c0 = p[0], c1 = p[1], c2 = p[2], c3 = p[3];
#pragma unroll 1
  for (int s = 0; s < NS; s += 8) {
    int np_ = (s + 8 < NS) ? (s + 8) >> 1 : 0;
    float4 n0 = p[np_], n1 = p[np_ + 1], n2 = p[np_ + 2], n3 = p[np_ + 3];
    float f0, f1, f2, f3, f4, f5, f6, f7;
    SSTEP(c0.x, c0.y, f0); SSTEP(c0.z, c0.w, f1);
    SSTEP(c1.x, c1.y, f2); SSTEP(c1.z, c1.w, f3);
    SSTEP(c2.x, c2.y, f4); SSTEP(c2.z, c2.w, f5);
    SSTEP(c3.x, c3.y, f6); SSTEP(c3.z, c3.w, f7);
    *(float4*)(fbrow + s) = make_float4(f0, f1, f2, f3);
    *(float4*)(fbrow + s + 4) = make_float4(f4, f5, f6, f7);
    c0 = n0; c1 = n1; c2 = n2; c3 = n3;
  }
  *H0 = 2.0f * R - P;
}

// coalesced column sum: inflow[j] = sum_i fb[i*NS + j]
static __device__ __forceinline__ float colsum(const float* __restrict__ col) {
  float a0=0,a1=0,a2=0,a3=0,a4=0,a5=0,a6=0,a7=0;
  float b0=0,b1=0,b2=0,b3=0,b4=0,b5=0,b6=0,b7=0;
#pragma unroll 1
  for (int i = 0; i < NB; i += 16) {
    const float* p = col + (size_t)i * NS;
    a0 += p[0ull*NS];  a1 += p[1ull*NS];  a2 += p[2ull*NS];  a3 += p[3ull*NS];
    a4 += p[4ull*NS];  a5 += p[5ull*NS];  a6 += p[6ull*NS];  a7 += p[7ull*NS];
    b0 += p[8ull*NS];  b1 += p[9ull*NS];  b2 += p[10ull*NS]; b3 += p[11ull*NS];
    b4 += p[12ull*NS]; b5 += p[13ull*NS]; b6 += p[14ull*NS]; b7 += p[15ull*NS];
  }
  return (((a0+a1)+(a2+a3))+((a4+a5)+(a6+a7))) + (((b0+b1)+(b2+b3))+((b4+b5)+(b6+b7)));
}

// ---------------- init ----------------
__global__ void init_k(const float* __restrict__ Hinit, const float* __restrict__ precip,
                       const float2* __restrict__ kh0, float* __restrict__ H,
                       float* __restrict__ fb0, float* __restrict__ out) {
  if (blockIdx.x == 30) {  // embedded layer0 scan for t=0
    if (threadIdx.x == 0) scan0(kh0, fb0, H, Hinit[0] + precip[0] * 0.2f);
    return;
  }
  int i = blockIdx.x * 256 + threadIdx.x;
  if (i < 5 * NB && i != 0) H[i] = Hinit[i];  // H[0] written by scan0
  if (i < TSTEPS) out[i] = 0.0f;
}

// ---------------- layer scan, coalesced, 4-bank pipelined ----------------
// MODE 0: layer1 (inflow = fb0 vector; extra block 24 runs layer0 scan for t+1)
// MODE 1: layers 2,3 (inflow = colsum of fb_in)
#define LOADB(P0,P1,P2,P3,P4,P5,P6,P7, sp)                        \
  { const float2* q_ = kh + (size_t)(sp) * NB + j;                \
    P0 = q_[0];          P1 = q_[(size_t)NB];                     \
    P2 = q_[2*(size_t)NB]; P3 = q_[3*(size_t)NB];                 \
    P4 = q_[4*(size_t)NB]; P5 = q_[5*(size_t)NB];                 \
    P6 = q_[6*(size_t)NB]; P7 = q_[7*(size_t)NB]; }

#define CONSB(P0,P1,P2,P3,P4,P5,P6,P7, sb)                        \
  { float f0_,f1_,f2_,f3_,f4_,f5_,f6_,f7_;                        \
    SSTEP(P0.x,P0.y,f0_); SSTEP(P1.x,P1.y,f1_);                   \
    SSTEP(P2.x,P2.y,f2_); SSTEP(P3.x,P3.y,f3_);                   \
    SSTEP(P4.x,P4.y,f4_); SSTEP(P5.x,P5.y,f5_);                   \
    SSTEP(P6.x,P6.y,f6_); SSTEP(P7.x,P7.y,f7_);                   \
    *(float4*)(fbr + (sb))     = make_float4(f0_,f1_,f2_,f3_);    \
    *(float4*)(fbr + (sb) + 4) = make_float4(f4_,f5_,f6_,f7_); }

template <int MODE>
__global__ __launch_bounds__(64) void scanN_k(
    const float2* __restrict__ kh,          // khT slice for this layer
    const float* __restrict__ inflow_src,   // MODE0: fb0 cur vec; MODE1: fb matrix
    float* __restrict__ fb_out,
    float* __restrict__ Hl,
    const float* __restrict__ precip, int t,
    const float2* __restrict__ kh0, float* __restrict__ fb0_next,
    float* __restrict__ H0) {
  if (MODE == 0 && blockIdx.x == 24) {  // embedded layer0 scan for t+1
    if (threadIdx.x == 0 && t + 1 < TSTEPS)
      scan0(kh0, fb0_next, H0, H0[0] + precip[t + 1] * 0.2f);
    return;
  }
  int j = blockIdx.x * 64 + threadIdx.x;
  float ppl = precip[t] * 0.2f;
  float inflow = ppl * (1.0f / NB);
  if (MODE == 0) inflow += inflow_src[j];
  else           inflow += colsum(inflow_src + j);
  float P = Hl[j] + inflow;
  float R = P;
  float* fbr = fb_out + (size_t)j * NS;
  float2 A0,A1,A2,A3,A4,A5,A6,A7, B0,B1,B2,B3,B4,B5,B6,B7;
  float2 C0,C1,C2,C3,C4,C5,C6,C7, D0,D1,D2,D3,D4,D5,D6,D7;
  LOADB(A0,A1,A2,A3,A4,A5,A6,A7, 0)
  LOADB(B0,B1,B2,B3,B4,B5,B6,B7, 8)
  LOADB(C0,C1,C2,C3,C4,C5,C6,C7, 16)
  LOADB(D0,D1,D2,D3,D4,D5,D6,D7, 24)
#pragma unroll 1
  for (int s = 0; s < NS; s += 32) {
    int s1 = (s + 32 < NS) ? s + 32 : 0;  // wrap prefetch (results unused)
    CONSB(A0,A1,A2,A3,A4,A5,A6,A7, s)
    LOADB(A0,A1,A2,A3,A4,A5,A6,A7, s1)
    CONSB(B0,B1,B2,B3,B4,B5,B6,B7, s + 8)
    LOADB(B0,B1,B2,B3,B4,B5,B6,B7, s1 + 8)
    CONSB(C0,C1,C2,C3,C4,C5,C6,C7, s + 16)
    LOADB(C0,C1,C2,C3,C4,C5,C6,C7, s1 + 16)
    CONSB(D0,D1,D2,D3,D4,D5,D6,D7, s + 24)
    LOADB(D0,D1,D2,D3,D4,D5,D6,D7, s1 + 24)
  }
  Hl[j] = 2.0f * R - P;
}

// ---------------- layer4: colsum + single spigot + reduce ----------------
__global__ __launch_bounds__(64) void scan4_k(const float2* __restrict__ kh4,
                                              const float* __restrict__ fb_in,
                                              float* __restrict__ H4,
                                              const float* __restrict__ precip, int t,
                                              float* __restrict__ out) {
  int j = blockIdx.x * 64 + threadIdx.x;
  float ppl = precip[t] * 0.2f;
  float inflow = ppl * (1.0f / NB) + colsum(fb_in + j);
  float P = H4[j] + inflow;
  float2 kh = kh4[j];
  float e = fmaxf(P - kh.y, 0.0f);
  float fl = kh.x * asqrt(e);
  H4[j] = P - fl;
  for (int o = 32; o; o >>= 1) fl += __shfl_xor(fl, o);
  if (threadIdx.x == 0) atomicAdd(out + t, fl);
}

extern "C" void kernel_launch(void* const* d_in, const int* in_sizes, int n_in,
                              void* d_out, int out_size, void* d_ws,
                              size_t ws_size, hipStream_t stream) {
  const float* theta = (const float*)d_in[0];
  const float* sp_h = (const float*)d_in[1];
  const float* sp_a = (const float*)d_in[2];
  const float* Hinit = (const float*)d_in[3];
  const float* precip = (const float*)d_in[4];
  float* out = (float*)d_out;

  char* ws = (char*)d_ws;
  float2* khT = (float2*)(ws + OFF_KHT);
  float2* kh0 = (float2*)(ws + OFF_KH0);
  float2* kh4 = (float2*)(ws + OFF_KH4);
  float* H = (float*)(ws + OFF_H);
  float* fb0 = (float*)(ws + OFF_FB0);   // [2][NS]
  float* fbA = (float*)(ws + OFF_FBA);
  float* fbB = (float*)(ws + OFF_FBB);

  hipLaunchKernelGGL(prep_small_k, dim3(6), dim3(256), 0, stream, theta, sp_h,
                     sp_a, kh0, kh4);
  hipLaunchKernelGGL(transpose_k, dim3(24, 24, 3), dim3(256), 0, stream, theta,
                     sp_h, sp_a, khT);
  hipLaunchKernelGGL(init_k, dim3(31), dim3(256), 0, stream, Hinit, precip, kh0,
                     H, fb0, out);

  for (int t = 0; t < TSTEPS; ++t) {
    const float* fb0cur = fb0 + (t & 1) * NS;
    float* fb0nxt = fb0 + ((t + 1) & 1) * NS;
    // layer1 (+ embedded layer0 for t+1)
    hipLaunchKernelGGL(scanN_k<0>, dim3(25), dim3(64), 0, stream,
                       khT + 0ull * NS * NB, fb0cur, fbA, H + 1 * NB, precip, t,
                       kh0, fb0nxt, H);
    // layer2
    hipLaunchKernelGGL(scanN_k<1>, dim3(24), dim3(64), 0, stream,
                       khT + 1ull * NS * NB, fbA, fbB, H + 2 * NB, precip, t,
                       kh0, (float*)nullptr, H);
    // layer3
    hipLaunchKernelGGL(scanN_k<1>, dim3(24), dim3(64), 0, stream,
                       khT + 2ull * NS * NB, fbB, fbA, H + 3 * NB, precip, t,
                       kh0, (float*)nullptr, H);
    // layer4 + outflow
    hipLaunchKernelGGL(scan4_k, dim3(24), dim3(64), 0, stream, kh4, fbA,
                       H + 4 * NB, precip, t, out);
  }
}

// Round 3
// 552.914 us; speedup vs baseline: 6.4548x; 2.4909x over previous
//
#include <hip/hip_runtime.h>

#define NB 1536
#define NS 1536
#define TSTEPS 4
#define KC  4.4294469180704688f  /* sqrt(2*9.81) */
#define HKC 2.2147234590352344f  /* 0.5*sqrt(2*9.81) */

// ---------------- ws layout (bytes) ----------------
#define OFF_KHT 0ull                                   // float2[3][NS][NB] (halfk,h)
#define OFF_KH0 (OFF_KHT + 3ull * NS * NB * 8)         // float2[NS]  layer0 bucket0
#define OFF_KH4 (OFF_KH0 + (unsigned long long)NS * 8) // float2[NB]  layer4 spigot0 (full k)
#define OFF_H   (OFF_KH4 + (unsigned long long)NB * 8) // float[5*NB]
#define OFF_FB0 (OFF_H + 5ull * NB * 4)                // float[2][NS] layer0 flows/2
#define OFF_PART (OFF_FB0 + 2ull * NS * 4)             // float[3][2][24][NS] partial flow/2 sums

static __device__ __forceinline__ float asqrt(float x) { return __builtin_amdgcn_sqrtf(x); }

// chain: sub -> max -> sqrt -> fma ; fl = halfk*q forks off-chain into LDS
#define SSTEP2(HK, HY, SLOC)                \
  {                                         \
    float e_ = fmaxf(R - (HY), 0.0f);       \
    float q_ = asqrt(e_);                   \
    R = fmaf(-(HK), q_, R);                 \
    red[SLOC][lane] = (HK)*q_;              \
  }

#define LOADB(P0,P1,P2,P3,P4,P5,P6,P7, sp)                        \
  { const float2* q_ = kh + (size_t)(sp) * NB;                    \
    P0 = q_[0];            P1 = q_[(size_t)NB];                   \
    P2 = q_[2*(size_t)NB]; P3 = q_[3*(size_t)NB];                 \
    P4 = q_[4*(size_t)NB]; P5 = q_[5*(size_t)NB];                 \
    P6 = q_[6*(size_t)NB]; P7 = q_[7*(size_t)NB]; }

#define CONS8(P0,P1,P2,P3,P4,P5,P6,P7, SL)                        \
  { SSTEP2(P0.x,P0.y,(SL)+0) SSTEP2(P1.x,P1.y,(SL)+1)             \
    SSTEP2(P2.x,P2.y,(SL)+2) SSTEP2(P3.x,P3.y,(SL)+3)             \
    SSTEP2(P4.x,P4.y,(SL)+4) SSTEP2(P5.x,P5.y,(SL)+5)             \
    SSTEP2(P6.x,P6.y,(SL)+6) SSTEP2(P7.x,P7.y,(SL)+7) }

// ---------------- prep kernels ----------------
__global__ __launch_bounds__(256) void prep_small_k(const float* __restrict__ th,
                                                    const float* __restrict__ hh,
                                                    const float* __restrict__ aa,
                                                    float2* __restrict__ kh0,
                                                    float2* __restrict__ kh4) {
  int i = blockIdx.x * 256 + threadIdx.x;
  if (i >= NS) return;
  kh0[i] = make_float2(th[i] * aa[i] * HKC, hh[i]);   // theta[0][0][i], halfk
  size_t i4 = ((size_t)4 * NB + i) * NS;              // theta[4][i][0], full k
  kh4[i] = make_float2(th[i4] * aa[i4] * KC, hh[i4]);
}

// khT[(l-1)][s][b] = { 0.5*theta*a*KC , h }
__global__ __launch_bounds__(256) void transpose_k(const float* __restrict__ th,
                                                   const float* __restrict__ hh,
                                                   const float* __restrict__ aa,
                                                   float2* __restrict__ khT) {
  __shared__ float2 tile[64][65];
  int l = blockIdx.z + 1;
  int b0 = blockIdx.x * 64, s0 = blockIdx.y * 64;
  int lane = threadIdx.x & 63, ty = threadIdx.x >> 6;
  size_t base = (size_t)l * NB * NS;
#pragma unroll
  for (int r = 0; r < 64; r += 4) {
    int b = b0 + r + ty;
    size_t idx = base + (size_t)b * NS + s0 + lane;
    tile[r + ty][lane] = make_float2(th[idx] * aa[idx] * HKC, hh[idx]);
  }
  __syncthreads();
#pragma unroll
  for (int r = 0; r < 64; r += 4) {
    int s = s0 + r + ty;
    khT[((size_t)blockIdx.z * NS + s) * NB + b0 + lane] = tile[lane][r + ty];
  }
}

__global__ void init_k(const float* __restrict__ Hinit, float* __restrict__ H,
                       float* __restrict__ out) {
  int i = blockIdx.x * 256 + threadIdx.x;
  if (i < 5 * NB) H[i] = Hinit[i];
  if (i < TSTEPS) out[i] = 0.0f;
}

// ---------------- layer0 serial scan (single lane), stores fl=flow/2 ----------------
static __device__ void scan0(const float2* __restrict__ kh0, float* __restrict__ fbrow,
                             float* __restrict__ H0, float P) {
  float R = P;
  const float4* p = (const float4*)kh0;  // {hk0,h0,hk1,h1}
  float4 c0 = p[0], c1 = p[1], c2 = p[2], c3 = p[3];
#define SSTEP0(HK, HY, S)                                          \
  { float e_ = fmaxf(R - (HY), 0.0f); float q_ = asqrt(e_);        \
    R = fmaf(-(HK), q_, R); fbrow[S] = (HK)*q_; }
#pragma unroll 1
  for (int s = 0; s < NS; s += 8) {
    int np_ = (s + 8 < NS) ? (s + 8) >> 1 : 0;
    float4 n0 = p[np_], n1 = p[np_ + 1], n2 = p[np_ + 2], n3 = p[np_ + 3];
    SSTEP0(c0.x, c0.y, s + 0) SSTEP0(c0.z, c0.w, s + 1)
    SSTEP0(c1.x, c1.y, s + 2) SSTEP0(c1.z, c1.w, s + 3)
    SSTEP0(c2.x, c2.y, s + 4) SSTEP0(c2.z, c2.w, s + 5)
    SSTEP0(c3.x, c3.y, s + 6) SSTEP0(c3.z, c3.w, s + 7)
    c0 = n0; c1 = n1; c2 = n2; c3 = n3;
  }
  *H0 = 2.0f * R - P;
}

// ---------------- wavefront stage kernel ----------------
// blocks 0..23: layer1 (t=d-1); 24..47: layer2 (t=d-2); 48..71: layer3 (t=d-3)
// blocks 72..95: layer4 (t=d-4); block 96: layer0 (t=d)
__global__ __launch_bounds__(64) void stage_k(
    const float2* __restrict__ khT, const float2* __restrict__ kh0,
    const float2* __restrict__ kh4, float* __restrict__ H,
    float* __restrict__ fb0, float* __restrict__ part,
    const float* __restrict__ precip, float* __restrict__ out, int d) {
  __shared__ float red[32][64];
  int blk = blockIdx.x;
  int lane = threadIdx.x;

  if (blk == 96) {  // -------- layer0 --------
    int t = d;
    if (t >= TSTEPS || lane != 0) return;
    float P = H[0] + precip[t] * 0.2f;
    scan0(kh0, fb0 + (size_t)(t & 1) * NS, H, P);
    return;
  }
  int track = blk / 24, b = blk % 24;
  int l = track + 1;
  int t = d - l;
  if (t < 0 || t >= TSTEPS) return;
  int par = t & 1;
  float ppl = precip[t] * 0.2f;
  int j = b * 64 + lane;

  if (l == 4) {  // -------- layer4: partial-sum + single spigot + outflow --------
    const float* pr = part + ((size_t)(2 * 2 + par) * 24) * NS + j;
    float s_ = 0.f;
#pragma unroll
    for (int i = 0; i < 24; ++i) s_ += pr[(size_t)i * NS];
    float P = H[4 * NB + j] + 2.0f * s_ + ppl * (1.0f / NB);
    float2 kh = kh4[j];
    float e = fmaxf(P - kh.y, 0.0f);
    float fl = kh.x * asqrt(e);
    H[4 * NB + j] = P - fl;
    for (int o = 32; o; o >>= 1) fl += __shfl_xor(fl, o);
    if (lane == 0) atomicAdd(out + t, fl);
    return;
  }

  // -------- layers 1..3: coalesced pipelined scan + LDS chunk reduce --------
  float inf;
  if (l == 1) {
    inf = 2.0f * fb0[(size_t)par * NS + j];
  } else {
    const float* pr = part + ((size_t)((l - 2) * 2 + par) * 24) * NS + j;
    float s_ = 0.f;
#pragma unroll
    for (int i = 0; i < 24; ++i) s_ += pr[(size_t)i * NS];
    inf = 2.0f * s_;
  }
  float P = H[l * NB + j] + inf + ppl * (1.0f / NB);
  float R = P;
  const float2* kh = khT + (size_t)(l - 1) * NS * NB + j;
  float* part_row = part + ((size_t)((l - 1) * 2 + par) * 24 + b) * NS;

  float2 A0,A1,A2,A3,A4,A5,A6,A7, B0,B1,B2,B3,B4,B5,B6,B7;
  float2 C0,C1,C2,C3,C4,C5,C6,C7, D0,D1,D2,D3,D4,D5,D6,D7;
  LOADB(A0,A1,A2,A3,A4,A5,A6,A7, 0)
  LOADB(B0,B1,B2,B3,B4,B5,B6,B7, 8)
  LOADB(C0,C1,C2,C3,C4,C5,C6,C7, 16)
  LOADB(D0,D1,D2,D3,D4,D5,D6,D7, 24)
  int rs = lane >> 1, rh = (lane & 1) * 32;
#pragma unroll 1
  for (int s = 0; s < NS; s += 32) {
    int s1 = (s + 32 < NS) ? s + 32 : 0;  // wrap prefetch (unused results)
    CONS8(A0,A1,A2,A3,A4,A5,A6,A7, 0)
    LOADB(A0,A1,A2,A3,A4,A5,A6,A7, s1)
    CONS8(B0,B1,B2,B3,B4,B5,B6,B7, 8)
    LOADB(B0,B1,B2,B3,B4,B5,B6,B7, s1 + 8)
    CONS8(C0,C1,C2,C3,C4,C5,C6,C7, 16)
    LOADB(C0,C1,C2,C3,C4,C5,C6,C7, s1 + 16)
    CONS8(D0,D1,D2,D3,D4,D5,D6,D7, 24)
    LOADB(D0,D1,D2,D3,D4,D5,D6,D7, s1 + 24)
    // cross-lane reduce of this 32-step chunk: part_row[s+r] = sum over 64 lanes
    {
      const float* rowp = &red[rs][rh];
      float acc = 0.f;
#pragma unroll
      for (int c = 0; c < 32; ++c) acc += rowp[(c + lane) & 31];
      acc += __shfl_xor(acc, 1);
      if (!(lane & 1)) part_row[s + rs] = acc;
    }
  }
  H[l * NB + j] = 2.0f * R - P;
}

extern "C" void kernel_launch(void* const* d_in, const int* in_sizes, int n_in,
                              void* d_out, int out_size, void* d_ws,
                              size_t ws_size, hipStream_t stream) {
  const float* theta = (const float*)d_in[0];
  const float* sp_h = (const float*)d_in[1];
  const float* sp_a = (const float*)d_in[2];
  const float* Hinit = (const float*)d_in[3];
  const float* precip = (const float*)d_in[4];
  float* out = (float*)d_out;

  char* ws = (char*)d_ws;
  float2* khT = (float2*)(ws + OFF_KHT);
  float2* kh0 = (float2*)(ws + OFF_KH0);
  float2* kh4 = (float2*)(ws + OFF_KH4);
  float* H = (float*)(ws + OFF_H);
  float* fb0 = (float*)(ws + OFF_FB0);
  float* part = (float*)(ws + OFF_PART);

  hipLaunchKernelGGL(prep_small_k, dim3(6), dim3(256), 0, stream, theta, sp_h,
                     sp_a, kh0, kh4);
  hipLaunchKernelGGL(transpose_k, dim3(24, 24, 3), dim3(256), 0, stream, theta,
                     sp_h, sp_a, khT);
  hipLaunchKernelGGL(init_k, dim3(30), dim3(256), 0, stream, Hinit, H, out);

  for (int d = 0; d < TSTEPS + 4; ++d) {  // anti-diagonal wavefront, d = t + l
    hipLaunchKernelGGL(stage_k, dim3(97), dim3(64), 0, stream, khT, kh0, kh4, H,
                       fb0, part, precip, out, d);
  }
}

// Round 5
// 467.184 us; speedup vs baseline: 7.6392x; 1.1835x over previous
//
#include <hip/hip_runtime.h>

#define NB 1536
#define NS 1536
#define TSTEPS 4
#define KC  4.4294469180704688f  /* sqrt(2*9.81) */
#define HKC 2.2147234590352344f  /* 0.5*sqrt(2*9.81) */

// ---------------- ws layout (bytes) ----------------
#define OFF_KHT 0ull                                   // float2[3][NS][NB] (halfk,h)
#define OFF_KH0 (OFF_KHT + 3ull * NS * NB * 8)         // float2[NS]
#define OFF_KH4 (OFF_KH0 + (unsigned long long)NS * 8) // float2[NB]
#define OFF_H   (OFF_KH4 + (unsigned long long)NB * 8) // float[5*NB]
#define OFF_FB0 (OFF_H + 5ull * NB * 4)                // float[2][NS]
#define OFF_PART (OFF_FB0 + 2ull * NS * 4)             // float[3][2][24][NS]

static __device__ __forceinline__ float asqrt(float x) { return __builtin_amdgcn_sqrtf(x); }

// serial step: chain = sub -> max -> sqrt -> fma ; fl forks off-chain
#define SS0(HK, HY, F)                      \
  {                                         \
    float e_ = fmaxf(R - (HY), 0.0f);       \
    float q_ = asqrt(e_);                   \
    R = fmaf(-(HK), q_, R);                 \
    F = (HK)*q_;                            \
  }

// track step: fl goes to LDS red[SL][lane]
#define SST(HK, HY, SL)                     \
  {                                         \
    float e_ = fmaxf(R - (HY), 0.0f);       \
    float q_ = asqrt(e_);                   \
    R = fmaf(-(HK), q_, R);                 \
    red[SL][lane] = (HK)*q_;                \
  }

#define LB(P0,P1,P2,P3,P4,P5,P6,P7, sp)                           \
  { const float2* q_ = kh + (size_t)(sp) * NB;                    \
    P0 = q_[0];            P1 = q_[(size_t)NB];                   \
    P2 = q_[2*(size_t)NB]; P3 = q_[3*(size_t)NB];                 \
    P4 = q_[4*(size_t)NB]; P5 = q_[5*(size_t)NB];                 \
    P6 = q_[6*(size_t)NB]; P7 = q_[7*(size_t)NB]; }

#define CB(P0,P1,P2,P3,P4,P5,P6,P7, SL)                           \
  { SST(P0.x,P0.y,(SL)+0) SST(P1.x,P1.y,(SL)+1)                   \
    SST(P2.x,P2.y,(SL)+2) SST(P3.x,P3.y,(SL)+3)                   \
    SST(P4.x,P4.y,(SL)+4) SST(P5.x,P5.y,(SL)+5)                   \
    SST(P6.x,P6.y,(SL)+6) SST(P7.x,P7.y,(SL)+7) }

// ---------------- layer0 serial scan from LDS, depth-2-group prefetch ----------------
static __device__ void scan0_lds(const float4* __restrict__ k0, float* __restrict__ fbrow,
                                 float* __restrict__ H0, float P) {
  float R = P;
  float4 c0 = k0[0], c1 = k0[1], c2 = k0[2], c3 = k0[3];
  float4 n0 = k0[4], n1 = k0[5], n2 = k0[6], n3 = k0[7];
#pragma unroll 1
  for (int g = 0; g < NS / 8; ++g) {
    int mi = (g + 2 < NS / 8) ? 4 * g + 8 : 0;  // group g+2 (wrap dummy)
    float4 m0 = k0[mi], m1 = k0[mi + 1], m2 = k0[mi + 2], m3 = k0[mi + 3];
    float f0, f1, f2, f3, f4, f5, f6, f7;
    SS0(c0.x, c0.y, f0) SS0(c0.z, c0.w, f1)
    SS0(c1.x, c1.y, f2) SS0(c1.z, c1.w, f3)
    SS0(c2.x, c2.y, f4) SS0(c2.z, c2.w, f5)
    SS0(c3.x, c3.y, f6) SS0(c3.z, c3.w, f7)
    ((float4*)fbrow)[2 * g]     = make_float4(f0, f1, f2, f3);
    ((float4*)fbrow)[2 * g + 1] = make_float4(f4, f5, f6, f7);
    c0 = n0; c1 = n1; c2 = n2; c3 = n3;
    n0 = m0; n1 = m1; n2 = m2; n3 = m3;
  }
  *H0 = 2.0f * R - P;
}

// ---------------- prep: fused tables + H init + out zero ----------------
__global__ __launch_bounds__(256) void prep_k(const float* __restrict__ th,
                                              const float* __restrict__ hh,
                                              const float* __restrict__ aa,
                                              const float* __restrict__ Hinit,
                                              float2* __restrict__ kh0,
                                              float2* __restrict__ kh4,
                                              float* __restrict__ H,
                                              float* __restrict__ out) {
  int i = blockIdx.x * 256 + threadIdx.x;
  if (i < NS) {
    kh0[i] = make_float2(th[i] * aa[i] * HKC, hh[i]);     // theta[0][0][i], halfk
    size_t i4 = ((size_t)4 * NB + i) * NS;                // theta[4][i][0], full k
    kh4[i] = make_float2(th[i4] * aa[i4] * KC, hh[i4]);
  }
  if (i < 5 * NB && i != 0) H[i] = Hinit[i];  // H[0] written by embedded scan0(t=0)
  if (i < TSTEPS) out[i] = 0.0f;
}

// ---------------- transpose (l=1..3) + embedded layer0 scan t=0 ----------------
// khT[(l-1)][s][b] = { 0.5*theta*a*KC , h }
__global__ __launch_bounds__(256) void transpose_k(const float* __restrict__ th,
                                                   const float* __restrict__ hh,
                                                   const float* __restrict__ aa,
                                                   float2* __restrict__ khT,
                                                   const float2* __restrict__ kh0,
                                                   const float* __restrict__ Hinit,
                                                   const float* __restrict__ precip,
                                                   float* __restrict__ H,
                                                   float* __restrict__ fb0) {
  __shared__ float2 tile[64][65];
  __shared__ float4 k0lds[NS / 2];
  if (blockIdx.z == 3) {  // embedded layer0 scan for t=0
    if (blockIdx.x || blockIdx.y) return;
    int lane = threadIdx.x;
    for (int i = lane; i < NS / 2; i += 256) k0lds[i] = ((const float4*)kh0)[i];
    __syncthreads();
    if (lane) return;
    scan0_lds(k0lds, fb0 /*par 0*/, H, Hinit[0] + precip[0] * 0.2f);
    return;
  }
  int l = blockIdx.z + 1;
  int b0 = blockIdx.x * 64, s0 = blockIdx.y * 64;
  int lane = threadIdx.x & 63, ty = threadIdx.x >> 6;
  size_t base = (size_t)l * NB * NS;
#pragma unroll
  for (int r = 0; r < 64; r += 4) {
    int b = b0 + r + ty;
    size_t idx = base + (size_t)b * NS + s0 + lane;
    tile[r + ty][lane] = make_float2(th[idx] * aa[idx] * HKC, hh[idx]);
  }
  __syncthreads();
#pragma unroll
  for (int r = 0; r < 64; r += 4) {
    int s = s0 + r + ty;
    khT[((size_t)blockIdx.z * NS + s) * NB + b0 + lane] = tile[lane][r + ty];
  }
}

// ---------------- wavefront stage kernel ----------------
// blocks 0..23: layer1 (t=d-1); 24..47: layer2 (t=d-2); 48..71: layer3 (t=d-3)
// blocks 72..95: layer4 (t=d-4); block 96: layer0 (t=d)
__global__ __launch_bounds__(64) void stage_k(
    const float2* __restrict__ khT, const float2* __restrict__ kh0,
    const float2* __restrict__ kh4, float* __restrict__ H,
    float* __restrict__ fb0, float* __restrict__ part,
    const float* __restrict__ precip, float* __restrict__ out, int d) {
  __shared__ float red[64][64];
  __shared__ float4 k0lds[NS / 2];
  int blk = blockIdx.x;
  int lane = threadIdx.x;

  if (blk == 96) {  // -------- layer0, t=d --------
    int t = d;
    if (t >= TSTEPS) return;
    for (int i = lane; i < NS / 2; i += 64) k0lds[i] = ((const float4*)kh0)[i];
    __syncthreads();
    if (lane) return;
    scan0_lds(k0lds, fb0 + (size_t)(t & 1) * NS, H, H[0] + precip[t] * 0.2f);
    return;
  }
  int track = blk / 24, b = blk % 24;
  int l = track + 1;
  int t = d - l;
  if (t < 0 || t >= TSTEPS) return;
  int par = t & 1;
  float ppl = precip[t] * 0.2f;
  int j = b * 64 + lane;

  if (l == 4) {  // -------- layer4: partial-sum + single spigot + outflow --------
    const float* pr = part + ((size_t)(2 * 2 + par) * 24) * NS + j;
    float s_ = 0.f;
#pragma unroll
    for (int i = 0; i < 24; ++i) s_ += pr[(size_t)i * NS];
    float P = H[4 * NB + j] + 2.0f * s_ + ppl * (1.0f / NB);
    float2 kh = kh4[j];
    float e = fmaxf(P - kh.y, 0.0f);
    float fl = kh.x * asqrt(e);
    H[4 * NB + j] = P - fl;
    for (int o = 32; o; o >>= 1) fl += __shfl_xor(fl, o);
    if (lane == 0) atomicAdd(out + t, fl);
    return;
  }

  // -------- layers 1..3: 64-step-deep register pipeline + LDS reduce --------
  float inf;
  if (l == 1) {
    inf = 2.0f * fb0[(size_t)par * NS + j];
  } else {
    const float* pr = part + ((size_t)((l - 2) * 2 + par) * 24) * NS + j;
    float s_ = 0.f;
#pragma unroll
    for (int i = 0; i < 24; ++i) s_ += pr[(size_t)i * NS];
    inf = 2.0f * s_;
  }
  float P = H[l * NB + j] + inf + ppl * (1.0f / NB);
  float R = P;
  const float2* kh = khT + (size_t)(l - 1) * NS * NB + j;
  float* part_row = part + ((size_t)((l - 1) * 2 + par) * 24 + b) * NS;

  // 8 banks x 8 float2 = 2 chunks of 32 steps in flight
  float2 A0,A1,A2,A3,A4,A5,A6,A7, B0,B1,B2,B3,B4,B5,B6,B7;
  float2 C0,C1,C2,C3,C4,C5,C6,C7, D0,D1,D2,D3,D4,D5,D6,D7;
  float2 E0,E1,E2,E3,E4,E5,E6,E7, F0,F1,F2,F3,F4,F5,F6,F7;
  float2 G0,G1,G2,G3,G4,G5,G6,G7, X0,X1,X2,X3,X4,X5,X6,X7;
  LB(A0,A1,A2,A3,A4,A5,A6,A7, 0)
  LB(B0,B1,B2,B3,B4,B5,B6,B7, 8)
  LB(C0,C1,C2,C3,C4,C5,C6,C7, 16)
  LB(D0,D1,D2,D3,D4,D5,D6,D7, 24)
  LB(E0,E1,E2,E3,E4,E5,E6,E7, 32)
  LB(F0,F1,F2,F3,F4,F5,F6,F7, 40)
  LB(G0,G1,G2,G3,G4,G5,G6,G7, 48)
  LB(X0,X1,X2,X3,X4,X5,X6,X7, 56)
#pragma unroll 1
  for (int s = 0; s < NS; s += 64) {
    int sA = (s + 64 < NS) ? s + 64 : 0;   // chunk +2 (wrap dummy)
    int sE = (s + 96 < NS) ? s + 96 : 0;   // chunk +3 (wrap dummy)
    CB(A0,A1,A2,A3,A4,A5,A6,A7, 0)   LB(A0,A1,A2,A3,A4,A5,A6,A7, sA)
    CB(B0,B1,B2,B3,B4,B5,B6,B7, 8)   LB(B0,B1,B2,B3,B4,B5,B6,B7, sA + 8)
    CB(C0,C1,C2,C3,C4,C5,C6,C7, 16)  LB(C0,C1,C2,C3,C4,C5,C6,C7, sA + 16)
    CB(D0,D1,D2,D3,D4,D5,D6,D7, 24)  LB(D0,D1,D2,D3,D4,D5,D6,D7, sA + 24)
    CB(E0,E1,E2,E3,E4,E5,E6,E7, 32)  LB(E0,E1,E2,E3,E4,E5,E6,E7, sE)
    CB(F0,F1,F2,F3,F4,F5,F6,F7, 40)  LB(F0,F1,F2,F3,F4,F5,F6,F7, sE + 8)
    CB(G0,G1,G2,G3,G4,G5,G6,G7, 48)  LB(G0,G1,G2,G3,G4,G5,G6,G7, sE + 16)
    CB(X0,X1,X2,X3,X4,X5,X6,X7, 56)  LB(X0,X1,X2,X3,X4,X5,X6,X7, sE + 24)
    // reduce: lane L sums step s+L across the 64 buckets (rotated float4 reads)
    {
      const float4* rowq = (const float4*)&red[lane][0];
      float a0 = 0.f, a1 = 0.f, a2 = 0.f, a3 = 0.f;
#pragma unroll
      for (int c = 0; c < 16; ++c) {
        float4 v = rowq[(c + lane) & 15];
        a0 += v.x; a1 += v.y; a2 += v.z; a3 += v.w;
      }
      part_row[s + lane] = (a0 + a1) + (a2 + a3);
    }
  }
  H[l * NB + j] = 2.0f * R - P;
}

extern "C" void kernel_launch(void* const* d_in, const int* in_sizes, int n_in,
                              void* d_out, int out_size, void* d_ws,
                              size_t ws_size, hipStream_t stream) {
  const float* theta = (const float*)d_in[0];
  const float* sp_h = (const float*)d_in[1];
  const float* sp_a = (const float*)d_in[2];
  const float* Hinit = (const float*)d_in[3];
  const float* precip = (const float*)d_in[4];
  float* out = (float*)d_out;

  char* ws = (char*)d_ws;
  float2* khT = (float2*)(ws + OFF_KHT);
  float2* kh0 = (float2*)(ws + OFF_KH0);
  float2* kh4 = (float2*)(ws + OFF_KH4);
  float* H = (float*)(ws + OFF_H);
  float* fb0 = (float*)(ws + OFF_FB0);
  float* part = (float*)(ws + OFF_PART);

  hipLaunchKernelGGL(prep_k, dim3(30), dim3(256), 0, stream, theta, sp_h, sp_a,
                     Hinit, kh0, kh4, H, out);
  hipLaunchKernelGGL(transpose_k, dim3(24, 24, 4), dim3(256), 0, stream, theta,
                     sp_h, sp_a, khT, kh0, Hinit, precip, H, fb0);
  for (int d = 1; d < TSTEPS + 4; ++d) {  // anti-diagonal wavefront, d = t + l
    hipLaunchKernelGGL(stage_k, dim3(97), dim3(64), 0, stream, khT, kh0, kh4, H,
                       fb0, part, precip, out, d);
  }
}